// Round 11
// baseline (731.198 us; speedup 1.0000x reference)
//
#include <hip/hip_runtime.h>
#include <hip/hip_bf16.h>
#include <math.h>

#define N_NODES 50000
#define N_EDGES 800000
#define IN_FEAT 8
#define HDIM 128
#define NLAYERS 6
#define NUM_GRAPHS 64
#define EPS_MSG 1e-7f
#define EPS_SM 1e-16f
#define LN_EPS 1e-5f
#define SCAN_NB 49       // ceil(50000/1024)
#define DUMMY_ROW 50115  // 0xC3C3
#define CSR_CAP 1600000  // >= sum of padded degrees (<=1.55M)

typedef __attribute__((ext_vector_type(8))) short short8;
typedef __attribute__((ext_vector_type(4))) float floatx4;
typedef __attribute__((ext_vector_type(2))) float floatx2;

__device__ __forceinline__ ushort f2bf(float x) {
    __hip_bfloat16 h = __float2bfloat16(x);
    return *reinterpret_cast<ushort*>(&h);
}
__device__ __forceinline__ float bf2f(ushort u) {
    unsigned int v = ((unsigned int)u) << 16;
    return __uint_as_float(v);
}
__device__ __forceinline__ ushort pk_fp8(float a, float b) {
    int r = __builtin_amdgcn_cvt_pk_fp8_f32(a, b, 0, false);
    return (ushort)(r & 0xffff);
}
__device__ __forceinline__ floatx2 upk_fp8(ushort v) {
    return __builtin_amdgcn_cvt_pk_f32_fp8((int)(unsigned)v, false);
}

// ---------------- node encoder + LN + ReLU (layer 0): X(bf16), Hb(fp8) ----------------
__global__ void k_encode_ln(const float* __restrict__ xin, const float* __restrict__ W,
                            const float* __restrict__ bias, const float* __restrict__ g0,
                            const float* __restrict__ b0, ushort* __restrict__ X,
                            ushort* __restrict__ Hb8) {
    __shared__ float sW[IN_FEAT * HDIM];
    int tid = threadIdx.x;
    int wid = tid >> 6, lane = tid & 63;
    for (int i = tid; i < IN_FEAT * HDIM; i += 256) sW[i] = W[i];
    __syncthreads();
    int n = blockIdx.x * 4 + wid;
    if (n >= N_NODES) return;
    int c0 = 2 * lane, c1 = 2 * lane + 1;
    float a0 = bias[c0], a1 = bias[c1];
#pragma unroll
    for (int f = 0; f < IN_FEAT; ++f) {
        float xf = xin[n * IN_FEAT + f];
        a0 += xf * sW[f * HDIM + c0];
        a1 += xf * sW[f * HDIM + c1];
    }
    ushort2 xv; xv.x = f2bf(a0); xv.y = f2bf(a1);
    *(ushort2*)(X + (size_t)n * HDIM + c0) = xv;
    float s = a0 + a1, sq = a0 * a0 + a1 * a1;
#pragma unroll
    for (int off = 32; off; off >>= 1) {
        s += __shfl_xor(s, off, 64);
        sq += __shfl_xor(sq, off, 64);
    }
    float mean = s * (1.f / 128.f);
    float var = sq * (1.f / 128.f) - mean * mean;
    float inv = rsqrtf(var + LN_EPS);
    float h0 = (a0 - mean) * inv * g0[c0] + b0[c0];
    float h1 = (a1 - mean) * inv * g0[c1] + b0[c1];
    Hb8[(size_t)n * 64 + lane] = pk_fp8(fmaxf(h0, 0.f), fmaxf(h1, 0.f));
}

// ---------------- CSR build (padded-to-16 segments) ----------------
__global__ void k_hist(const int* __restrict__ dst, int* __restrict__ deg) {
    int i = blockIdx.x * blockDim.x + threadIdx.x;
    if (i < N_EDGES) atomicAdd(&deg[dst[i]], 1);
}

__global__ void k_bsum(const int* __restrict__ deg, int* __restrict__ bsum) {
    int i = blockIdx.x * 1024 + threadIdx.x;
    int v = (i < N_NODES) ? ((deg[i] + 15) & ~15) : 0;
#pragma unroll
    for (int off = 32; off; off >>= 1) v += __shfl_xor(v, off, 64);
    __shared__ int wsum[16];
    int wid = threadIdx.x >> 6;
    if ((threadIdx.x & 63) == 0) wsum[wid] = v;
    __syncthreads();
    if (threadIdx.x < 16) {
        int s = wsum[threadIdx.x];
#pragma unroll
        for (int off = 8; off; off >>= 1) s += __shfl_xor(s, off, 16);
        if (threadIdx.x == 0) bsum[blockIdx.x] = s;
    }
}

__global__ void k_scan_small(int* __restrict__ bsum) {
    int lane = threadIdx.x;  // 0..63
    int orig = (lane < SCAN_NB) ? bsum[lane] : 0;
    int v = orig;
#pragma unroll
    for (int off = 1; off < 64; off <<= 1) {
        int u = __shfl_up(v, off, 64);
        if (lane >= off) v += u;
    }
    if (lane < SCAN_NB) bsum[lane] = v - orig;  // exclusive
}

__global__ void k_scan_final(const int* __restrict__ deg, const int* __restrict__ bsum,
                             int* __restrict__ row_ptr, int* __restrict__ cursor) {
    __shared__ int wsum[16];
    int i = blockIdx.x * 1024 + threadIdx.x;
    int t = threadIdx.x;
    int lane = t & 63, wid = t >> 6;
    int orig = (i < N_NODES) ? ((deg[i] + 15) & ~15) : 0;
    int v = orig;
#pragma unroll
    for (int off = 1; off < 64; off <<= 1) {
        int u = __shfl_up(v, off, 64);
        if (lane >= off) v += u;
    }
    if (lane == 63) wsum[wid] = v;
    __syncthreads();
    if (t < 16) {
        int s = wsum[t];
#pragma unroll
        for (int off = 1; off < 16; off <<= 1) {
            int u = __shfl_up(s, off, 16);
            if (t >= off) s += u;
        }
        wsum[t] = s;
    }
    __syncthreads();
    int base = bsum[blockIdx.x] + (wid ? wsum[wid - 1] : 0);
    int excl = base + v - orig;
    if (i < N_NODES) {
        row_ptr[i] = excl;
        cursor[i] = excl;
        if (i == N_NODES - 1) row_ptr[N_NODES] = excl + orig;
    }
}

__global__ void k_scatter(const int* __restrict__ src, const int* __restrict__ dst,
                          int* __restrict__ cursor, ushort* __restrict__ csr_src) {
    int i = blockIdx.x * blockDim.x + threadIdx.x;
    if (i < N_EDGES) {
        int pos = atomicAdd(&cursor[dst[i]], 1);
        csr_src[pos] = (ushort)src[i];
    }
}

// ---------------- weight prefragment: fp32 -> bf16 MFMA B-frag layout ----------------
__global__ void k_prep(const float* __restrict__ W1, const float* __restrict__ W2,
                       ushort* __restrict__ Wp1, ushort* __restrict__ Wp2) {
    int idx = blockIdx.x * 256 + threadIdx.x;
    if (idx < 24576) {
        int lane = idx & 63;
        int frag = idx >> 6;
        int cf = frag & 15, kb = (frag >> 4) & 3, l = frag >> 6;
        const float* Wl = W1 + (size_t)l * 128 * 256;
        ushort* o = Wp1 + (size_t)idx * 8;
        int k0 = kb * 32 + (lane >> 4) * 8;
        int c = cf * 16 + (lane & 15);
#pragma unroll
        for (int j = 0; j < 8; ++j) o[j] = f2bf(Wl[(k0 + j) * 256 + c]);
    } else if (idx < 49152) {
        int i2 = idx - 24576;
        int lane = i2 & 63;
        int frag = i2 >> 6;
        int cf = frag & 7, kb = (frag >> 3) & 7, l = frag >> 6;
        const float* Wl = W2 + (size_t)l * 256 * 128;
        ushort* o = Wp2 + (size_t)i2 * 8;
        int k0 = kb * 32 + (lane >> 4) * 8;
        int c = cf * 16 + (lane & 15);
#pragma unroll
        for (int j = 0; j < 8; ++j) o[j] = f2bf(Wl[(k0 + j) * 128 + c]);
    }
}

// ---------------- softmax aggregation: 1 wave/node, padded guard-free loop ----------------
// Dummy slots point at a -256 fp8 row => exp2 = 0 exactly (zero contribution).
// EPS_MSG deferred: e = exp2(f*ts) (uniform-scale-invariant); num += EPS*den at the end.
__global__ __launch_bounds__(256) void k_aggr(const ushort* __restrict__ Hb8,
                                              const int* __restrict__ row_ptr,
                                              const ushort* __restrict__ csr,
                                              const float* __restrict__ t_all,
                                              int layer, ushort* __restrict__ U) {
    int tid = threadIdx.x;
    int wid = tid >> 6, lane = tid & 63;
    int n = blockIdx.x * 4 + wid;   // 12500*4 = 50000 exact
    float ts = t_all[layer] * 1.44269504f;
    int beg = row_ptr[n];
    int cntp = row_ptr[n + 1] - beg;   // multiple of 16
    float den0 = 0.f, den1 = 0.f, num0 = 0.f, num1 = 0.f;
    unsigned lo = (unsigned)(lane << 1);

    for (int p = 0; p < cntp; p += 8) {
        short8 cs = *(const short8*)(csr + beg + p);  // 8 indices, one 16B load
        ushort q0, q1, q2, q3, q4, q5, q6, q7;
        q0 = *(const ushort*)((const char*)Hb8 + (((unsigned)(ushort)cs[0]) << 7) + lo);
        q1 = *(const ushort*)((const char*)Hb8 + (((unsigned)(ushort)cs[1]) << 7) + lo);
        q2 = *(const ushort*)((const char*)Hb8 + (((unsigned)(ushort)cs[2]) << 7) + lo);
        q3 = *(const ushort*)((const char*)Hb8 + (((unsigned)(ushort)cs[3]) << 7) + lo);
        q4 = *(const ushort*)((const char*)Hb8 + (((unsigned)(ushort)cs[4]) << 7) + lo);
        q5 = *(const ushort*)((const char*)Hb8 + (((unsigned)(ushort)cs[5]) << 7) + lo);
        q6 = *(const ushort*)((const char*)Hb8 + (((unsigned)(ushort)cs[6]) << 7) + lo);
        q7 = *(const ushort*)((const char*)Hb8 + (((unsigned)(ushort)cs[7]) << 7) + lo);
#define PROC(Q)                                  \
        {                                        \
            floatx2 f = upk_fp8(Q);              \
            float e0 = exp2f(f.x * ts);          \
            float e1 = exp2f(f.y * ts);          \
            den0 += e0; num0 = fmaf(f.x, e0, num0); \
            den1 += e1; num1 = fmaf(f.y, e1, num1); \
        }
        PROC(q0) PROC(q1) PROC(q2) PROC(q3)
        PROC(q4) PROC(q5) PROC(q6) PROC(q7)
#undef PROC
    }

    num0 = fmaf(EPS_MSG, den0, num0);
    num1 = fmaf(EPS_MSG, den1, num1);
    floatx2 hs = upk_fp8(*(const ushort*)((const char*)Hb8 + (((unsigned)n) << 7) + lo));
    ushort2 o;
    o.x = f2bf(num0 / (den0 + EPS_SM) + hs.x);
    o.y = f2bf(num1 / (den1 + EPS_SM) + hs.y);
    *(ushort2*)(U + (size_t)n * 128 + 2 * lane) = o;
}

// ---- fused MLP: X(bf16) += W2^T(relu(LN(U@W1+b1)))+b2; epilogue LN+ReLU -> Hb8(next layer) ----
__global__ __launch_bounds__(256) void k_mlp_fused(
    const ushort* __restrict__ U, ushort* __restrict__ X,
    const short8* __restrict__ Wp1, const short8* __restrict__ Wp2,
    const float* __restrict__ b1, const float* __restrict__ mg,
    const float* __restrict__ mb, const float* __restrict__ b2,
    const float* __restrict__ nlg, const float* __restrict__ nlb,
    unsigned char* __restrict__ Hb8Out, int writeHb) {
    __shared__ ushort sBuf[64 * 264];
    __shared__ float sStat[4][64][2];
    __shared__ float sMV[64][2];
    int tid = threadIdx.x;
    int w = tid >> 6, lane = tid & 63;
    int g = lane >> 4, c15 = lane & 15;
    int n0 = blockIdx.x * 64;

#pragma unroll
    for (int i = 0; i < 4; ++i) {
        int id = tid + i * 256;
        int row = id >> 4, cc = id & 15;
        int n = n0 + row;
        short8 v = {0, 0, 0, 0, 0, 0, 0, 0};
        if (n < N_NODES) v = *(const short8*)(U + (size_t)n * 128 + cc * 8);
        *(short8*)(sBuf + row * 136 + cc * 8) = v;
    }
    __syncthreads();

    floatx4 acc1[4][4];
#pragma unroll
    for (int rf = 0; rf < 4; ++rf)
#pragma unroll
        for (int cf = 0; cf < 4; ++cf) acc1[rf][cf] = (floatx4){0.f, 0.f, 0.f, 0.f};

#pragma unroll
    for (int kb = 0; kb < 4; ++kb) {
        short8 bfr[4];
#pragma unroll
        for (int cf = 0; cf < 4; ++cf) bfr[cf] = Wp1[(kb * 16 + w * 4 + cf) * 64 + lane];
        short8 af[4];
#pragma unroll
        for (int rf = 0; rf < 4; ++rf)
            af[rf] = *(const short8*)(sBuf + (rf * 16 + c15) * 136 + kb * 32 + g * 8);
#pragma unroll
        for (int rf = 0; rf < 4; ++rf)
#pragma unroll
            for (int cf = 0; cf < 4; ++cf)
                acc1[rf][cf] = __builtin_amdgcn_mfma_f32_16x16x32_bf16(af[rf], bfr[cf], acc1[rf][cf], 0, 0, 0);
    }

    int colb = w * 64;
    float bv[4], gv[4], bbv[4];
#pragma unroll
    for (int cf = 0; cf < 4; ++cf) {
        int c = colb + cf * 16 + c15;
        bv[cf] = b1[c]; gv[cf] = mg[c]; bbv[cf] = mb[c];
    }
    float sS[4][4], sQ[4][4];
#pragma unroll
    for (int rf = 0; rf < 4; ++rf)
#pragma unroll
        for (int reg = 0; reg < 4; ++reg) {
            float s = 0.f, q = 0.f;
#pragma unroll
            for (int cf = 0; cf < 4; ++cf) {
                float v = acc1[rf][cf][reg] + bv[cf];
                acc1[rf][cf][reg] = v;
                s += v; q += v * v;
            }
            sS[rf][reg] = s; sQ[rf][reg] = q;
        }
#pragma unroll
    for (int off = 1; off < 16; off <<= 1)
#pragma unroll
        for (int rf = 0; rf < 4; ++rf)
#pragma unroll
            for (int reg = 0; reg < 4; ++reg) {
                sS[rf][reg] += __shfl_xor(sS[rf][reg], off, 64);
                sQ[rf][reg] += __shfl_xor(sQ[rf][reg], off, 64);
            }
    if (c15 == 0) {
#pragma unroll
        for (int rf = 0; rf < 4; ++rf)
#pragma unroll
            for (int reg = 0; reg < 4; ++reg) {
                int row = rf * 16 + g * 4 + reg;
                sStat[w][row][0] = sS[rf][reg];
                sStat[w][row][1] = sQ[rf][reg];
            }
    }
    __syncthreads();
    if (tid < 64) {
        float s = sStat[0][tid][0] + sStat[1][tid][0] + sStat[2][tid][0] + sStat[3][tid][0];
        float q = sStat[0][tid][1] + sStat[1][tid][1] + sStat[2][tid][1] + sStat[3][tid][1];
        float mean = s * (1.f / 256.f);
        float var = q * (1.f / 256.f) - mean * mean;
        sMV[tid][0] = mean;
        sMV[tid][1] = rsqrtf(var + LN_EPS);
    }
    __syncthreads();

#pragma unroll
    for (int rf = 0; rf < 4; ++rf)
#pragma unroll
        for (int reg = 0; reg < 4; ++reg) {
            int row = rf * 16 + g * 4 + reg;
            float mean = sMV[row][0], inv = sMV[row][1];
#pragma unroll
            for (int cf = 0; cf < 4; ++cf) {
                float v = (acc1[rf][cf][reg] - mean) * inv * gv[cf] + bbv[cf];
                sBuf[row * 264 + colb + cf * 16 + c15] = f2bf(fmaxf(v, 0.f));
            }
        }
    __syncthreads();

    floatx4 acc2[4][2];
#pragma unroll
    for (int rf = 0; rf < 4; ++rf) {
        acc2[rf][0] = (floatx4){0.f, 0.f, 0.f, 0.f};
        acc2[rf][1] = (floatx4){0.f, 0.f, 0.f, 0.f};
    }
#pragma unroll
    for (int kb = 0; kb < 8; ++kb) {
        short8 bfr[2];
#pragma unroll
        for (int cf = 0; cf < 2; ++cf) bfr[cf] = Wp2[(kb * 8 + w * 2 + cf) * 64 + lane];
        short8 af[4];
#pragma unroll
        for (int rf = 0; rf < 4; ++rf)
            af[rf] = *(const short8*)(sBuf + (rf * 16 + c15) * 264 + kb * 32 + g * 8);
#pragma unroll
        for (int rf = 0; rf < 4; ++rf)
#pragma unroll
            for (int cf = 0; cf < 2; ++cf)
                acc2[rf][cf] = __builtin_amdgcn_mfma_f32_16x16x32_bf16(af[rf], bfr[cf], acc2[rf][cf], 0, 0, 0);
    }

    float b2v[2];
    b2v[0] = b2[w * 32 + c15];
    b2v[1] = b2[w * 32 + 16 + c15];
    float gn[2] = {0.f, 0.f}, bn[2] = {0.f, 0.f};
    if (writeHb) {
        gn[0] = nlg[w * 32 + c15];      bn[0] = nlb[w * 32 + c15];
        gn[1] = nlg[w * 32 + 16 + c15]; bn[1] = nlb[w * 32 + 16 + c15];
    }
#pragma unroll
    for (int rf = 0; rf < 4; ++rf)
#pragma unroll
        for (int reg = 0; reg < 4; ++reg) {
            int row = rf * 16 + g * 4 + reg;
            int n = n0 + row;
            float s = 0.f, q = 0.f;
#pragma unroll
            for (int cf = 0; cf < 2; ++cf) {
                float xold = (n < N_NODES) ? bf2f(X[(size_t)n * 128 + w * 32 + cf * 16 + c15]) : 0.f;
                float v = xold + acc2[rf][cf][reg] + b2v[cf];
                acc2[rf][cf][reg] = v;
                s += v; q += v * v;
            }
            if (writeHb) {
#pragma unroll
                for (int off = 1; off < 16; off <<= 1) {
                    s += __shfl_xor(s, off, 64);
                    q += __shfl_xor(q, off, 64);
                }
                if (c15 == 0) {
                    sStat[w][row][0] = s;
                    sStat[w][row][1] = q;
                }
            }
        }
    if (writeHb) {
        __syncthreads();
        if (tid < 64) {
            float s = sStat[0][tid][0] + sStat[1][tid][0] + sStat[2][tid][0] + sStat[3][tid][0];
            float q = sStat[0][tid][1] + sStat[1][tid][1] + sStat[2][tid][1] + sStat[3][tid][1];
            float mean = s * (1.f / 128.f);
            float var = q * (1.f / 128.f) - mean * mean;
            sMV[tid][0] = mean;
            sMV[tid][1] = rsqrtf(var + LN_EPS);
        }
        __syncthreads();
    }
#pragma unroll
    for (int rf = 0; rf < 4; ++rf)
#pragma unroll
        for (int reg = 0; reg < 4; ++reg) {
            int row = rf * 16 + g * 4 + reg;
            int n = n0 + row;
            if (n < N_NODES) {
                float mean = 0.f, inv = 0.f;
                if (writeHb) { mean = sMV[row][0]; inv = sMV[row][1]; }
#pragma unroll
                for (int cf = 0; cf < 2; ++cf) {
                    int col = w * 32 + cf * 16 + c15;
                    float v = acc2[rf][cf][reg];
                    X[(size_t)n * 128 + col] = f2bf(v);
                    if (writeHb) {
                        float h = fmaxf((v - mean) * inv * gn[cf] + bn[cf], 0.f);
                        int pk = __builtin_amdgcn_cvt_pk_fp8_f32(h, h, 0, false);
                        Hb8Out[(size_t)n * 128 + col] = (unsigned char)(pk & 0xff);
                    }
                }
            }
        }
}

// ---------------- global add pool (bf16 X) ----------------
__global__ void k_pool(const ushort* __restrict__ X, const int* __restrict__ batch,
                       float* __restrict__ out) {
    __shared__ int sBat[128];
    int c = threadIdx.x;
    int n0 = blockIdx.x * 128;
    int nend = n0 + 128; if (nend > N_NODES) nend = N_NODES;
    sBat[c] = (n0 + c < N_NODES) ? batch[n0 + c] : -1;
    __syncthreads();
    float acc = 0.f;
    int cur = sBat[0];
    for (int n = n0; n < nend; ++n) {
        int g = sBat[n - n0];
        if (g != cur) {
            atomicAdd(&out[cur * HDIM + c], acc);
            acc = 0.f;
            cur = g;
        }
        acc += bf2f(X[(size_t)n * HDIM + c]);
    }
    if (nend > n0) atomicAdd(&out[cur * HDIM + c], acc);
}

extern "C" void kernel_launch(void* const* d_in, const int* in_sizes, int n_in,
                              void* d_out, int out_size, void* d_ws, size_t ws_size,
                              hipStream_t stream) {
    const float* x_in   = (const float*)d_in[0];
    const int*   eidx   = (const int*)d_in[1];
    const int*   batch  = (const int*)d_in[2];
    const float* node_W = (const float*)d_in[3];
    const float* node_b = (const float*)d_in[4];
    const float* ln_g   = (const float*)d_in[5];
    const float* ln_b   = (const float*)d_in[6];
    const float* t_all  = (const float*)d_in[7];
    const float* W1     = (const float*)d_in[8];
    const float* b1     = (const float*)d_in[9];
    const float* mg     = (const float*)d_in[10];
    const float* mb     = (const float*)d_in[11];
    const float* W2     = (const float*)d_in[12];
    const float* b2     = (const float*)d_in[13];
    float* out = (float*)d_out;

    char* ws = (char*)d_ws;
    ushort* X    = (ushort*)(ws + 0);            // 12,800,000 B (bf16)
    ushort* Hb8  = (ushort*)(ws + 12800000);     // 6,414,848 B (fp8, 50116 rows x 128B)
    ushort* U    = (ushort*)(ws + 19216000);     // 12,800,000 B (bf16)
    ushort* Wp1  = (ushort*)(ws + 32016000);     // 393,216 B
    ushort* Wp2  = (ushort*)(ws + 32416000);     // 393,216 B
    int* deg     = (int*)(ws + 32816000);        // 200,000 B
    int* row_ptr = (int*)(ws + 33016064);        // 200,004 B
    int* cursor  = (int*)(ws + 33216128);        // 200,000 B
    ushort* csr_src = (ushort*)(ws + 33416128);  // 3,200,000 B (padded CSR)
    int* bsum    = (int*)(ws + 36616128);        // 256 B

    const int* e_src = eidx;
    const int* e_dst = eidx + N_EDGES;

    hipMemsetAsync(deg, 0, N_NODES * sizeof(int), stream);
    hipMemsetAsync(csr_src, 0xC3, CSR_CAP * sizeof(ushort), stream);  // pad = DUMMY_ROW
    hipMemsetAsync((char*)Hb8 + (size_t)DUMMY_ROW * 128, 0xF8, 128, stream);  // fp8 -256 row
    k_hist<<<(N_EDGES + 255) / 256, 256, 0, stream>>>(e_dst, deg);
    k_bsum<<<SCAN_NB, 1024, 0, stream>>>(deg, bsum);
    k_scan_small<<<1, 64, 0, stream>>>(bsum);
    k_scan_final<<<SCAN_NB, 1024, 0, stream>>>(deg, bsum, row_ptr, cursor);
    k_scatter<<<(N_EDGES + 255) / 256, 256, 0, stream>>>(e_src, e_dst, cursor, csr_src);
    k_prep<<<192, 256, 0, stream>>>(W1, W2, Wp1, Wp2);
    k_encode_ln<<<12500, 256, 0, stream>>>(x_in, node_W, node_b, ln_g, ln_b, X, Hb8);

    for (int l = 0; l < NLAYERS; ++l) {
        k_aggr<<<12500, 256, 0, stream>>>(Hb8, row_ptr, csr_src, t_all, l, U);
        int wh = (l < NLAYERS - 1) ? 1 : 0;
        const float* nlg = ln_g + (wh ? (l + 1) : 0) * HDIM;
        const float* nlb = ln_b + (wh ? (l + 1) : 0) * HDIM;
        k_mlp_fused<<<(N_NODES + 63) / 64, 256, 0, stream>>>(
            U, X,
            (const short8*)(Wp1 + (size_t)l * 32768), (const short8*)(Wp2 + (size_t)l * 32768),
            b1 + l * 256, mg + l * 256, mb + l * 256, b2 + l * 128,
            nlg, nlb, (unsigned char*)Hb8, wh);
    }

    hipMemsetAsync(out, 0, NUM_GRAPHS * HDIM * sizeof(float), stream);
    k_pool<<<(N_NODES + 127) / 128, 128, 0, stream>>>(X, batch, out);
}

// Round 12
// 635.119 us; speedup vs baseline: 1.1513x; 1.1513x over previous
//
#include <hip/hip_runtime.h>
#include <hip/hip_bf16.h>
#include <math.h>

#define N_NODES 50000
#define N_EDGES 800000
#define IN_FEAT 8
#define HDIM 128
#define NLAYERS 6
#define NUM_GRAPHS 64
#define EPS_MSG 1e-7f
#define EPS_SM 1e-16f
#define LN_EPS 1e-5f
#define SCAN_NB 49       // ceil(50000/1024)
#define DUMMY_ROW 50115  // 0xC3C3
#define CSR_CAP 1600000  // >= sum of padded degrees (<=1.55M)

typedef __attribute__((ext_vector_type(8))) short short8;
typedef __attribute__((ext_vector_type(4))) float floatx4;
typedef __attribute__((ext_vector_type(2))) float floatx2;

__device__ __forceinline__ ushort f2bf(float x) {
    __hip_bfloat16 h = __float2bfloat16(x);
    return *reinterpret_cast<ushort*>(&h);
}
__device__ __forceinline__ float bf2f(ushort u) {
    unsigned int v = ((unsigned int)u) << 16;
    return __uint_as_float(v);
}
__device__ __forceinline__ ushort pk_fp8(float a, float b) {
    int r = __builtin_amdgcn_cvt_pk_fp8_f32(a, b, 0, false);
    return (ushort)(r & 0xffff);
}
__device__ __forceinline__ floatx2 upk_fp8(ushort v) {
    return __builtin_amdgcn_cvt_pk_f32_fp8((int)(unsigned)v, false);
}
// raw v_exp_f32 (2^x). Valid: args here are in [-370, ~17], no fixup needed.
__device__ __forceinline__ float exp2_raw(float x) {
    float r;
    asm("v_exp_f32 %0, %1" : "=v"(r) : "v"(x));
    return r;
}

// ---------------- node encoder + LN + ReLU (layer 0): X(bf16), Hb(fp8) ----------------
__global__ void k_encode_ln(const float* __restrict__ xin, const float* __restrict__ W,
                            const float* __restrict__ bias, const float* __restrict__ g0,
                            const float* __restrict__ b0, ushort* __restrict__ X,
                            ushort* __restrict__ Hb8) {
    __shared__ float sW[IN_FEAT * HDIM];
    int tid = threadIdx.x;
    int wid = tid >> 6, lane = tid & 63;
    for (int i = tid; i < IN_FEAT * HDIM; i += 256) sW[i] = W[i];
    __syncthreads();
    int n = blockIdx.x * 4 + wid;
    if (n >= N_NODES) return;
    int c0 = 2 * lane, c1 = 2 * lane + 1;
    float a0 = bias[c0], a1 = bias[c1];
#pragma unroll
    for (int f = 0; f < IN_FEAT; ++f) {
        float xf = xin[n * IN_FEAT + f];
        a0 += xf * sW[f * HDIM + c0];
        a1 += xf * sW[f * HDIM + c1];
    }
    ushort2 xv; xv.x = f2bf(a0); xv.y = f2bf(a1);
    *(ushort2*)(X + (size_t)n * HDIM + c0) = xv;
    float s = a0 + a1, sq = a0 * a0 + a1 * a1;
#pragma unroll
    for (int off = 32; off; off >>= 1) {
        s += __shfl_xor(s, off, 64);
        sq += __shfl_xor(sq, off, 64);
    }
    float mean = s * (1.f / 128.f);
    float var = sq * (1.f / 128.f) - mean * mean;
    float inv = rsqrtf(var + LN_EPS);
    float h0 = (a0 - mean) * inv * g0[c0] + b0[c0];
    float h1 = (a1 - mean) * inv * g0[c1] + b0[c1];
    Hb8[(size_t)n * 64 + lane] = pk_fp8(fmaxf(h0, 0.f), fmaxf(h1, 0.f));
}

// ---------------- CSR build (padded-to-16 segments) ----------------
__global__ void k_hist(const int* __restrict__ dst, int* __restrict__ deg) {
    int i = blockIdx.x * blockDim.x + threadIdx.x;
    if (i < N_EDGES) atomicAdd(&deg[dst[i]], 1);
}

__global__ void k_bsum(const int* __restrict__ deg, int* __restrict__ bsum) {
    int i = blockIdx.x * 1024 + threadIdx.x;
    int v = (i < N_NODES) ? ((deg[i] + 15) & ~15) : 0;
#pragma unroll
    for (int off = 32; off; off >>= 1) v += __shfl_xor(v, off, 64);
    __shared__ int wsum[16];
    int wid = threadIdx.x >> 6;
    if ((threadIdx.x & 63) == 0) wsum[wid] = v;
    __syncthreads();
    if (threadIdx.x < 16) {
        int s = wsum[threadIdx.x];
#pragma unroll
        for (int off = 8; off; off >>= 1) s += __shfl_xor(s, off, 16);
        if (threadIdx.x == 0) bsum[blockIdx.x] = s;
    }
}

__global__ void k_scan_small(int* __restrict__ bsum) {
    int lane = threadIdx.x;  // 0..63
    int orig = (lane < SCAN_NB) ? bsum[lane] : 0;
    int v = orig;
#pragma unroll
    for (int off = 1; off < 64; off <<= 1) {
        int u = __shfl_up(v, off, 64);
        if (lane >= off) v += u;
    }
    if (lane < SCAN_NB) bsum[lane] = v - orig;  // exclusive
}

__global__ void k_scan_final(const int* __restrict__ deg, const int* __restrict__ bsum,
                             int* __restrict__ row_ptr, int* __restrict__ cursor) {
    __shared__ int wsum[16];
    int i = blockIdx.x * 1024 + threadIdx.x;
    int t = threadIdx.x;
    int lane = t & 63, wid = t >> 6;
    int orig = (i < N_NODES) ? ((deg[i] + 15) & ~15) : 0;
    int v = orig;
#pragma unroll
    for (int off = 1; off < 64; off <<= 1) {
        int u = __shfl_up(v, off, 64);
        if (lane >= off) v += u;
    }
    if (lane == 63) wsum[wid] = v;
    __syncthreads();
    if (t < 16) {
        int s = wsum[t];
#pragma unroll
        for (int off = 1; off < 16; off <<= 1) {
            int u = __shfl_up(s, off, 16);
            if (t >= off) s += u;
        }
        wsum[t] = s;
    }
    __syncthreads();
    int base = bsum[blockIdx.x] + (wid ? wsum[wid - 1] : 0);
    int excl = base + v - orig;
    if (i < N_NODES) {
        row_ptr[i] = excl;
        cursor[i] = excl;
        if (i == N_NODES - 1) row_ptr[N_NODES] = excl + orig;
    }
}

__global__ void k_scatter(const int* __restrict__ src, const int* __restrict__ dst,
                          int* __restrict__ cursor, ushort* __restrict__ csr_src) {
    int i = blockIdx.x * blockDim.x + threadIdx.x;
    if (i < N_EDGES) {
        int pos = atomicAdd(&cursor[dst[i]], 1);
        csr_src[pos] = (ushort)src[i];
    }
}

// ---------------- weight prefragment: fp32 -> bf16 MFMA B-frag layout ----------------
__global__ void k_prep(const float* __restrict__ W1, const float* __restrict__ W2,
                       ushort* __restrict__ Wp1, ushort* __restrict__ Wp2) {
    int idx = blockIdx.x * 256 + threadIdx.x;
    if (idx < 24576) {
        int lane = idx & 63;
        int frag = idx >> 6;
        int cf = frag & 15, kb = (frag >> 4) & 3, l = frag >> 6;
        const float* Wl = W1 + (size_t)l * 128 * 256;
        ushort* o = Wp1 + (size_t)idx * 8;
        int k0 = kb * 32 + (lane >> 4) * 8;
        int c = cf * 16 + (lane & 15);
#pragma unroll
        for (int j = 0; j < 8; ++j) o[j] = f2bf(Wl[(k0 + j) * 256 + c]);
    } else if (idx < 49152) {
        int i2 = idx - 24576;
        int lane = i2 & 63;
        int frag = i2 >> 6;
        int cf = frag & 7, kb = (frag >> 3) & 7, l = frag >> 6;
        const float* Wl = W2 + (size_t)l * 256 * 128;
        ushort* o = Wp2 + (size_t)i2 * 8;
        int k0 = kb * 32 + (lane >> 4) * 8;
        int c = cf * 16 + (lane & 15);
#pragma unroll
        for (int j = 0; j < 8; ++j) o[j] = f2bf(Wl[(k0 + j) * 128 + c]);
    }
}

// ---------------- softmax aggregation: 2 waves/node, padded guard-free loop, raw v_exp ----------------
// Dummy slots point at a -256 fp8 row => 2^(-369) = 0 exactly (zero contribution).
// EPS_MSG deferred: e = 2^(f*ts) (uniform-scale-invariant); num += EPS*den at the end.
__global__ __launch_bounds__(256) void k_aggr(const ushort* __restrict__ Hb8,
                                              const int* __restrict__ row_ptr,
                                              const ushort* __restrict__ csr,
                                              const float* __restrict__ t_all,
                                              int layer, ushort* __restrict__ U) {
    __shared__ float part[2][64][4];
    int tid = threadIdx.x;
    int wid = tid >> 6, lane = tid & 63;
    int local = wid >> 1;   // node slot (0..1)
    int half = wid & 1;     // edge-half
    int n = blockIdx.x * 2 + local;   // 25000*2 = 50000 exact
    float ts = t_all[layer] * 1.44269504f;
    int beg = row_ptr[n];
    int cntp = row_ptr[n + 1] - beg;   // multiple of 16
    int mycnt = cntp >> 1;             // multiple of 8
    int myBeg = beg + half * mycnt;    // contiguous halves
    float den0 = 0.f, den1 = 0.f, num0 = 0.f, num1 = 0.f;
    unsigned lo = (unsigned)(lane << 1);

    for (int p = 0; p < mycnt; p += 8) {
        short8 cs = *(const short8*)(csr + myBeg + p);  // 8 indices, one 16B load
        ushort q0, q1, q2, q3, q4, q5, q6, q7;
        q0 = *(const ushort*)((const char*)Hb8 + (((unsigned)(ushort)cs[0]) << 7) + lo);
        q1 = *(const ushort*)((const char*)Hb8 + (((unsigned)(ushort)cs[1]) << 7) + lo);
        q2 = *(const ushort*)((const char*)Hb8 + (((unsigned)(ushort)cs[2]) << 7) + lo);
        q3 = *(const ushort*)((const char*)Hb8 + (((unsigned)(ushort)cs[3]) << 7) + lo);
        q4 = *(const ushort*)((const char*)Hb8 + (((unsigned)(ushort)cs[4]) << 7) + lo);
        q5 = *(const ushort*)((const char*)Hb8 + (((unsigned)(ushort)cs[5]) << 7) + lo);
        q6 = *(const ushort*)((const char*)Hb8 + (((unsigned)(ushort)cs[6]) << 7) + lo);
        q7 = *(const ushort*)((const char*)Hb8 + (((unsigned)(ushort)cs[7]) << 7) + lo);
#define PROC(Q)                                     \
        {                                           \
            floatx2 f = upk_fp8(Q);                 \
            float e0 = exp2_raw(f.x * ts);          \
            float e1 = exp2_raw(f.y * ts);          \
            den0 += e0; num0 = fmaf(f.x, e0, num0); \
            den1 += e1; num1 = fmaf(f.y, e1, num1); \
        }
        PROC(q0) PROC(q1) PROC(q2) PROC(q3)
        PROC(q4) PROC(q5) PROC(q6) PROC(q7)
#undef PROC
    }

    if (half == 1) {
        part[local][lane][0] = num0;
        part[local][lane][1] = num1;
        part[local][lane][2] = den0;
        part[local][lane][3] = den1;
    }
    __syncthreads();
    if (half == 0) {
        num0 += part[local][lane][0];
        num1 += part[local][lane][1];
        den0 += part[local][lane][2];
        den1 += part[local][lane][3];
        num0 = fmaf(EPS_MSG, den0, num0);
        num1 = fmaf(EPS_MSG, den1, num1);
        floatx2 hs = upk_fp8(*(const ushort*)((const char*)Hb8 + (((unsigned)n) << 7) + lo));
        ushort2 o;
        o.x = f2bf(num0 / (den0 + EPS_SM) + hs.x);
        o.y = f2bf(num1 / (den1 + EPS_SM) + hs.y);
        *(ushort2*)(U + (size_t)n * 128 + 2 * lane) = o;
    }
}

// ---- fused MLP: X(bf16) += W2^T(relu(LN(U@W1+b1)))+b2; epilogue LN+ReLU -> Hb8(next layer) ----
__global__ __launch_bounds__(256) void k_mlp_fused(
    const ushort* __restrict__ U, ushort* __restrict__ X,
    const short8* __restrict__ Wp1, const short8* __restrict__ Wp2,
    const float* __restrict__ b1, const float* __restrict__ mg,
    const float* __restrict__ mb, const float* __restrict__ b2,
    const float* __restrict__ nlg, const float* __restrict__ nlb,
    unsigned char* __restrict__ Hb8Out, int writeHb) {
    __shared__ ushort sBuf[64 * 264];
    __shared__ float sStat[4][64][2];
    __shared__ float sMV[64][2];
    int tid = threadIdx.x;
    int w = tid >> 6, lane = tid & 63;
    int g = lane >> 4, c15 = lane & 15;
    int n0 = blockIdx.x * 64;

#pragma unroll
    for (int i = 0; i < 4; ++i) {
        int id = tid + i * 256;
        int row = id >> 4, cc = id & 15;
        int n = n0 + row;
        short8 v = {0, 0, 0, 0, 0, 0, 0, 0};
        if (n < N_NODES) v = *(const short8*)(U + (size_t)n * 128 + cc * 8);
        *(short8*)(sBuf + row * 136 + cc * 8) = v;
    }
    __syncthreads();

    floatx4 acc1[4][4];
#pragma unroll
    for (int rf = 0; rf < 4; ++rf)
#pragma unroll
        for (int cf = 0; cf < 4; ++cf) acc1[rf][cf] = (floatx4){0.f, 0.f, 0.f, 0.f};

#pragma unroll
    for (int kb = 0; kb < 4; ++kb) {
        short8 bfr[4];
#pragma unroll
        for (int cf = 0; cf < 4; ++cf) bfr[cf] = Wp1[(kb * 16 + w * 4 + cf) * 64 + lane];
        short8 af[4];
#pragma unroll
        for (int rf = 0; rf < 4; ++rf)
            af[rf] = *(const short8*)(sBuf + (rf * 16 + c15) * 136 + kb * 32 + g * 8);
#pragma unroll
        for (int rf = 0; rf < 4; ++rf)
#pragma unroll
            for (int cf = 0; cf < 4; ++cf)
                acc1[rf][cf] = __builtin_amdgcn_mfma_f32_16x16x32_bf16(af[rf], bfr[cf], acc1[rf][cf], 0, 0, 0);
    }

    int colb = w * 64;
    float bv[4], gv[4], bbv[4];
#pragma unroll
    for (int cf = 0; cf < 4; ++cf) {
        int c = colb + cf * 16 + c15;
        bv[cf] = b1[c]; gv[cf] = mg[c]; bbv[cf] = mb[c];
    }
    float sS[4][4], sQ[4][4];
#pragma unroll
    for (int rf = 0; rf < 4; ++rf)
#pragma unroll
        for (int reg = 0; reg < 4; ++reg) {
            float s = 0.f, q = 0.f;
#pragma unroll
            for (int cf = 0; cf < 4; ++cf) {
                float v = acc1[rf][cf][reg] + bv[cf];
                acc1[rf][cf][reg] = v;
                s += v; q += v * v;
            }
            sS[rf][reg] = s; sQ[rf][reg] = q;
        }
#pragma unroll
    for (int off = 1; off < 16; off <<= 1)
#pragma unroll
        for (int rf = 0; rf < 4; ++rf)
#pragma unroll
            for (int reg = 0; reg < 4; ++reg) {
                sS[rf][reg] += __shfl_xor(sS[rf][reg], off, 64);
                sQ[rf][reg] += __shfl_xor(sQ[rf][reg], off, 64);
            }
    if (c15 == 0) {
#pragma unroll
        for (int rf = 0; rf < 4; ++rf)
#pragma unroll
            for (int reg = 0; reg < 4; ++reg) {
                int row = rf * 16 + g * 4 + reg;
                sStat[w][row][0] = sS[rf][reg];
                sStat[w][row][1] = sQ[rf][reg];
            }
    }
    __syncthreads();
    if (tid < 64) {
        float s = sStat[0][tid][0] + sStat[1][tid][0] + sStat[2][tid][0] + sStat[3][tid][0];
        float q = sStat[0][tid][1] + sStat[1][tid][1] + sStat[2][tid][1] + sStat[3][tid][1];
        float mean = s * (1.f / 256.f);
        float var = q * (1.f / 256.f) - mean * mean;
        sMV[tid][0] = mean;
        sMV[tid][1] = rsqrtf(var + LN_EPS);
    }
    __syncthreads();

#pragma unroll
    for (int rf = 0; rf < 4; ++rf)
#pragma unroll
        for (int reg = 0; reg < 4; ++reg) {
            int row = rf * 16 + g * 4 + reg;
            float mean = sMV[row][0], inv = sMV[row][1];
#pragma unroll
            for (int cf = 0; cf < 4; ++cf) {
                float v = (acc1[rf][cf][reg] - mean) * inv * gv[cf] + bbv[cf];
                sBuf[row * 264 + colb + cf * 16 + c15] = f2bf(fmaxf(v, 0.f));
            }
        }
    __syncthreads();

    floatx4 acc2[4][2];
#pragma unroll
    for (int rf = 0; rf < 4; ++rf) {
        acc2[rf][0] = (floatx4){0.f, 0.f, 0.f, 0.f};
        acc2[rf][1] = (floatx4){0.f, 0.f, 0.f, 0.f};
    }
#pragma unroll
    for (int kb = 0; kb < 8; ++kb) {
        short8 bfr[2];
#pragma unroll
        for (int cf = 0; cf < 2; ++cf) bfr[cf] = Wp2[(kb * 8 + w * 2 + cf) * 64 + lane];
        short8 af[4];
#pragma unroll
        for (int rf = 0; rf < 4; ++rf)
            af[rf] = *(const short8*)(sBuf + (rf * 16 + c15) * 264 + kb * 32 + g * 8);
#pragma unroll
        for (int rf = 0; rf < 4; ++rf)
#pragma unroll
            for (int cf = 0; cf < 2; ++cf)
                acc2[rf][cf] = __builtin_amdgcn_mfma_f32_16x16x32_bf16(af[rf], bfr[cf], acc2[rf][cf], 0, 0, 0);
    }

    float b2v[2];
    b2v[0] = b2[w * 32 + c15];
    b2v[1] = b2[w * 32 + 16 + c15];
    float gn[2] = {0.f, 0.f}, bn[2] = {0.f, 0.f};
    if (writeHb) {
        gn[0] = nlg[w * 32 + c15];      bn[0] = nlb[w * 32 + c15];
        gn[1] = nlg[w * 32 + 16 + c15]; bn[1] = nlb[w * 32 + 16 + c15];
    }
#pragma unroll
    for (int rf = 0; rf < 4; ++rf)
#pragma unroll
        for (int reg = 0; reg < 4; ++reg) {
            int row = rf * 16 + g * 4 + reg;
            int n = n0 + row;
            float s = 0.f, q = 0.f;
#pragma unroll
            for (int cf = 0; cf < 2; ++cf) {
                float xold = (n < N_NODES) ? bf2f(X[(size_t)n * 128 + w * 32 + cf * 16 + c15]) : 0.f;
                float v = xold + acc2[rf][cf][reg] + b2v[cf];
                acc2[rf][cf][reg] = v;
                s += v; q += v * v;
            }
            if (writeHb) {
#pragma unroll
                for (int off = 1; off < 16; off <<= 1) {
                    s += __shfl_xor(s, off, 64);
                    q += __shfl_xor(q, off, 64);
                }
                if (c15 == 0) {
                    sStat[w][row][0] = s;
                    sStat[w][row][1] = q;
                }
            }
        }
    if (writeHb) {
        __syncthreads();
        if (tid < 64) {
            float s = sStat[0][tid][0] + sStat[1][tid][0] + sStat[2][tid][0] + sStat[3][tid][0];
            float q = sStat[0][tid][1] + sStat[1][tid][1] + sStat[2][tid][1] + sStat[3][tid][1];
            float mean = s * (1.f / 128.f);
            float var = q * (1.f / 128.f) - mean * mean;
            sMV[tid][0] = mean;
            sMV[tid][1] = rsqrtf(var + LN_EPS);
        }
        __syncthreads();
    }
#pragma unroll
    for (int rf = 0; rf < 4; ++rf)
#pragma unroll
        for (int reg = 0; reg < 4; ++reg) {
            int row = rf * 16 + g * 4 + reg;
            int n = n0 + row;
            if (n < N_NODES) {
                float mean = 0.f, inv = 0.f;
                if (writeHb) { mean = sMV[row][0]; inv = sMV[row][1]; }
#pragma unroll
                for (int cf = 0; cf < 2; ++cf) {
                    int col = w * 32 + cf * 16 + c15;
                    float v = acc2[rf][cf][reg];
                    X[(size_t)n * 128 + col] = f2bf(v);
                    if (writeHb) {
                        float h = fmaxf((v - mean) * inv * gn[cf] + bn[cf], 0.f);
                        int pk = __builtin_amdgcn_cvt_pk_fp8_f32(h, h, 0, false);
                        Hb8Out[(size_t)n * 128 + col] = (unsigned char)(pk & 0xff);
                    }
                }
            }
        }
}

// ---------------- global add pool (bf16 X) ----------------
__global__ void k_pool(const ushort* __restrict__ X, const int* __restrict__ batch,
                       float* __restrict__ out) {
    __shared__ int sBat[128];
    int c = threadIdx.x;
    int n0 = blockIdx.x * 128;
    int nend = n0 + 128; if (nend > N_NODES) nend = N_NODES;
    sBat[c] = (n0 + c < N_NODES) ? batch[n0 + c] : -1;
    __syncthreads();
    float acc = 0.f;
    int cur = sBat[0];
    for (int n = n0; n < nend; ++n) {
        int g = sBat[n - n0];
        if (g != cur) {
            atomicAdd(&out[cur * HDIM + c], acc);
            acc = 0.f;
            cur = g;
        }
        acc += bf2f(X[(size_t)n * HDIM + c]);
    }
    if (nend > n0) atomicAdd(&out[cur * HDIM + c], acc);
}

extern "C" void kernel_launch(void* const* d_in, const int* in_sizes, int n_in,
                              void* d_out, int out_size, void* d_ws, size_t ws_size,
                              hipStream_t stream) {
    const float* x_in   = (const float*)d_in[0];
    const int*   eidx   = (const int*)d_in[1];
    const int*   batch  = (const int*)d_in[2];
    const float* node_W = (const float*)d_in[3];
    const float* node_b = (const float*)d_in[4];
    const float* ln_g   = (const float*)d_in[5];
    const float* ln_b   = (const float*)d_in[6];
    const float* t_all  = (const float*)d_in[7];
    const float* W1     = (const float*)d_in[8];
    const float* b1     = (const float*)d_in[9];
    const float* mg     = (const float*)d_in[10];
    const float* mb     = (const float*)d_in[11];
    const float* W2     = (const float*)d_in[12];
    const float* b2     = (const float*)d_in[13];
    float* out = (float*)d_out;

    char* ws = (char*)d_ws;
    ushort* X    = (ushort*)(ws + 0);            // 12,800,000 B (bf16)
    ushort* Hb8  = (ushort*)(ws + 12800000);     // 6,414,848 B (fp8, 50116 rows x 128B)
    ushort* U    = (ushort*)(ws + 19216000);     // 12,800,000 B (bf16)
    ushort* Wp1  = (ushort*)(ws + 32016000);     // 393,216 B
    ushort* Wp2  = (ushort*)(ws + 32416000);     // 393,216 B
    int* deg     = (int*)(ws + 32816000);        // 200,000 B
    int* row_ptr = (int*)(ws + 33016064);        // 200,004 B
    int* cursor  = (int*)(ws + 33216128);        // 200,000 B
    ushort* csr_src = (ushort*)(ws + 33416128);  // 3,200,000 B (padded CSR)
    int* bsum    = (int*)(ws + 36616128);        // 256 B

    const int* e_src = eidx;
    const int* e_dst = eidx + N_EDGES;

    hipMemsetAsync(deg, 0, N_NODES * sizeof(int), stream);
    hipMemsetAsync(csr_src, 0xC3, CSR_CAP * sizeof(ushort), stream);  // pad = DUMMY_ROW
    hipMemsetAsync((char*)Hb8 + (size_t)DUMMY_ROW * 128, 0xF8, 128, stream);  // fp8 -256 row
    k_hist<<<(N_EDGES + 255) / 256, 256, 0, stream>>>(e_dst, deg);
    k_bsum<<<SCAN_NB, 1024, 0, stream>>>(deg, bsum);
    k_scan_small<<<1, 64, 0, stream>>>(bsum);
    k_scan_final<<<SCAN_NB, 1024, 0, stream>>>(deg, bsum, row_ptr, cursor);
    k_scatter<<<(N_EDGES + 255) / 256, 256, 0, stream>>>(e_src, e_dst, cursor, csr_src);
    k_prep<<<192, 256, 0, stream>>>(W1, W2, Wp1, Wp2);
    k_encode_ln<<<12500, 256, 0, stream>>>(x_in, node_W, node_b, ln_g, ln_b, X, Hb8);

    for (int l = 0; l < NLAYERS; ++l) {
        k_aggr<<<25000, 256, 0, stream>>>(Hb8, row_ptr, csr_src, t_all, l, U);
        int wh = (l < NLAYERS - 1) ? 1 : 0;
        const float* nlg = ln_g + (wh ? (l + 1) : 0) * HDIM;
        const float* nlb = ln_b + (wh ? (l + 1) : 0) * HDIM;
        k_mlp_fused<<<(N_NODES + 63) / 64, 256, 0, stream>>>(
            U, X,
            (const short8*)(Wp1 + (size_t)l * 32768), (const short8*)(Wp2 + (size_t)l * 32768),
            b1 + l * 256, mg + l * 256, mb + l * 256, b2 + l * 128,
            nlg, nlb, (unsigned char*)Hb8, wh);
    }

    hipMemsetAsync(out, 0, NUM_GRAPHS * HDIM * sizeof(float), stream);
    k_pool<<<(N_NODES + 127) / 128, 128, 0, stream>>>(X, batch, out);
}